// Round 1
// baseline (4322.022 us; speedup 1.0000x reference)
//
#include <hip/hip_runtime.h>
#include <stdint.h>

typedef unsigned long long u64;
typedef unsigned short u16;

#define F_DIM 8192
#define U_DIM 8192
#define D_DIM 768
#define NTOK  2048
#define KSEL  64
#define COLCAP 544      // per-column entry capacity (mean 409.6, sigma 19.7 -> +6.8 sigma)
#define TILE  256       // f/u tile edge for mask processing
#define NFT   32        // F_DIM / TILE
#define NUT   32        // U_DIM / TILE
#define DCH   32        // d-chunk for virtual build
#define ENTCAP 3840     // per-tile entry capacity (mean 3277, sigma 55.8)
#define NBIN  1024

// ---------------------------------------------------------------------------
// K1: t_bias[f] = dot(W_enc[f,:], b_up0+b_up1) + b_enc[f]
// one wave per f
__global__ void k_bias(const float* __restrict__ Wenc, const float* __restrict__ benc,
                       const float* __restrict__ b0, const float* __restrict__ b1,
                       float* __restrict__ t_bias) {
    int wid = threadIdx.x >> 6, lane = threadIdx.x & 63;
    int f = blockIdx.x * 4 + wid;
    const float* row = Wenc + (size_t)f * D_DIM;
    float s = 0.f;
    for (int j = lane; j < D_DIM; j += 64) s += row[j] * (b0[j] + b1[j]);
    #pragma unroll
    for (int off = 32; off; off >>= 1) s += __shfl_down(s, off, 64);
    if (lane == 0) t_bias[f] = s + benc[f];
}

// ---------------------------------------------------------------------------
// K2: scan masks -> per-(layer,ftile) column counts + bitmaps (so the mask is
// read from HBM exactly once for counting+filling)
__global__ void k_mask_scan(const float* __restrict__ mask0, const float* __restrict__ mask1,
                            int* __restrict__ cnt_tile, u64* __restrict__ bitmap) {
    int ut = blockIdx.x, ft = blockIdx.y, l = blockIdx.z;
    const float* mask = l ? mask1 : mask0;
    int tid = threadIdx.x, lane = tid & 63, wid = tid >> 6;
    int u = ut * TILE + tid;
    int f0 = ft * TILE;
    u64* bm = bitmap + (((size_t)(l * NFT + ft) * NUT + ut) * TILE) * 4;
    int cnt = 0;
    for (int fl = 0; fl < TILE; ++fl) {
        float v = mask[(size_t)(f0 + fl) * U_DIM + u];
        int nz = (v != 0.0f);
        cnt += nz;
        u64 bal = __ballot(nz);
        if (lane == 0) bm[(size_t)fl * 4 + wid] = bal;
    }
    cnt_tile[(size_t)(l * NFT + ft) * U_DIM + u] = cnt;
}

// ---------------------------------------------------------------------------
// K3: per-column exclusive prefix over ftiles -> slot bases + clamped totals
__global__ void k_col_prefix(const int* __restrict__ cnt_tile, int* __restrict__ base,
                             int* __restrict__ cnt_tot) {
    int idx = blockIdx.x * blockDim.x + threadIdx.x;   // 0 .. 2*8192-1
    int l = idx >> 13, u = idx & (U_DIM - 1);
    int run = 0;
    for (int ft = 0; ft < NFT; ++ft) {
        int c = cnt_tile[(size_t)(l * NFT + ft) * U_DIM + u];
        base[(size_t)(l * NFT + ft) * U_DIM + u] = run;
        run += c;
    }
    cnt_tot[l * U_DIM + u] = run < COLCAP ? run : COLCAP;
}

// ---------------------------------------------------------------------------
// K4: build sparse virtual weights in CSC (by column u): f-indices + f32 values
// tile 256f x 256u; thread <-> column; W_up chunk in registers (reuse across
// the column's entries), W_enc chunk in LDS transposed (bank-spread b32 reads)
__global__ __launch_bounds__(256, 2) void k_virt_build(
        const float* __restrict__ Wenc, const float* __restrict__ Wup0,
        const float* __restrict__ Wup1, const u64* __restrict__ bitmap,
        const int* __restrict__ base, u16* __restrict__ csc_f, float* __restrict__ csc_v) {
    __shared__ u64 bm[TILE][4];                 // 8KB
    __shared__ int cs[TILE];                    // 1KB scan buffer
    __shared__ unsigned char entf[ENTCAP];      // 3.75KB
    __shared__ float acc[ENTCAP];               // 15KB
    __shared__ float we_t[DCH][TILE + 1];       // 32.1KB, transposed, bank-spread
    int ut = blockIdx.x, ft = blockIdx.y, l = blockIdx.z;
    const float* Wup = l ? Wup1 : Wup0;
    int tid = threadIdx.x;
    int u0 = ut * TILE, f0 = ft * TILE;

    const u64* gbm = bitmap + (((size_t)(l * NFT + ft) * NUT + ut) * TILE) * 4;
    for (int i = tid; i < TILE * 4; i += 256) ((u64*)bm)[i] = gbm[i];
    __syncthreads();

    int w = tid >> 6, b = tid & 63;
    int cnt = 0;
    for (int fl = 0; fl < TILE; ++fl) cnt += (int)((bm[fl][w] >> b) & 1ULL);
    cs[tid] = cnt;
    __syncthreads();
    for (int off = 1; off < 256; off <<= 1) {      // inclusive Hillis-Steele
        int v = (tid >= off) ? cs[tid - off] : 0;
        __syncthreads();
        cs[tid] += v;
        __syncthreads();
    }
    int cstart = cs[tid] - cnt;                    // exclusive
    // build per-column entry lists, ascending f (deterministic)
    {
        int i = 0;
        for (int fl = 0; fl < TILE; ++fl)
            if ((bm[fl][w] >> b) & 1ULL) {
                int p = cstart + i;
                if (p < ENTCAP) entf[p] = (unsigned char)fl;
                ++i;
            }
    }
    for (int i = tid; i < ENTCAP; i += 256) acc[i] = 0.f;
    __syncthreads();

    float wu[DCH];
    for (int d0 = 0; d0 < D_DIM; d0 += DCH) {
        const float* wr = Wenc + (size_t)(f0 + tid) * D_DIM + d0;
        #pragma unroll
        for (int j = 0; j < DCH; j += 4) {
            float4 t4 = *(const float4*)(wr + j);
            we_t[j][tid] = t4.x; we_t[j + 1][tid] = t4.y;
            we_t[j + 2][tid] = t4.z; we_t[j + 3][tid] = t4.w;
        }
        const float* ur = Wup + (size_t)(u0 + tid) * D_DIM + d0;
        #pragma unroll
        for (int j = 0; j < DCH; j += 4) {
            float4 t4 = *(const float4*)(ur + j);
            wu[j] = t4.x; wu[j + 1] = t4.y; wu[j + 2] = t4.z; wu[j + 3] = t4.w;
        }
        __syncthreads();
        for (int i = 0; i < cnt; ++i) {
            int p = cstart + i;
            if (p >= ENTCAP) break;
            int fl = entf[p];
            float s = 0.f;
            #pragma unroll
            for (int j = 0; j < DCH; ++j) s += we_t[j][fl] * wu[j];
            acc[p] += s;
        }
        __syncthreads();
    }
    // write out this column's entries to its CSC slots (ascending f per tile)
    int u = u0 + tid;
    int bse = base[(size_t)(l * NFT + ft) * U_DIM + u];
    size_t colbase = ((size_t)l * U_DIM + u) * COLCAP;
    for (int i = 0; i < cnt; ++i) {
        int p = cstart + i;
        if (p >= ENTCAP) break;
        int slot = bse + i;
        if (slot < COLCAP) {
            csc_f[colbase + slot] = (u16)(f0 + entf[p]);
            csc_v[colbase + slot] = acc[p];
        }
    }
}

// ---------------------------------------------------------------------------
// K5: per-token upstream contribution. One block per token; ballot over the
// pruned row finds nnz u's; each column's CSC entries are streamed coalesced
// and scattered into a 32KB LDS accumulator with f32 atomics. Writes the full
// approx row (contrib only; encoder added later) to C = d_out feat region.
__global__ __launch_bounds__(512) void k_contrib(
        const float* __restrict__ pruned0, const float* __restrict__ pruned1,
        const int* __restrict__ cnt_tot, const u16* __restrict__ csc_f,
        const float* __restrict__ csc_v, float* __restrict__ C) {
    __shared__ float accum[F_DIM];   // 32KB
    int t = blockIdx.x;
    int tid = threadIdx.x, lane = tid & 63, wid = tid >> 6;
    for (int i = tid; i < F_DIM; i += 512) accum[i] = 0.f;
    __syncthreads();
    for (int l = 0; l < 2; ++l) {
        const float* P = (l ? pruned1 : pruned0) + (size_t)t * U_DIM;
        const int* cl = cnt_tot + l * U_DIM;
        const u16* cf = csc_f + (size_t)l * U_DIM * COLCAP;
        const float* cv = csc_v + (size_t)l * U_DIM * COLCAP;
        for (int w = wid; w < U_DIM / 64; w += 8) {
            float pv = P[w * 64 + lane];
            u64 bal = __ballot(pv != 0.0f);
            while (bal) {
                int bb = __builtin_ctzll(bal);
                bal &= bal - 1;
                int u = w * 64 + bb;
                float p = __shfl(pv, bb, 64);
                int cn = cl[u];
                size_t cb = (size_t)u * COLCAP;
                for (int e = lane; e < cn; e += 64) {
                    int f = cf[cb + e];
                    float v = cv[cb + e];
                    atomicAdd(&accum[f], p * v);
                }
            }
        }
    }
    __syncthreads();
    float* Crow = C + (size_t)t * F_DIM;
    for (int i = tid; i < F_DIM; i += 512) Crow[i] = accum[i];
}

// ---------------------------------------------------------------------------
// K6: f32 encoder GEMM, C[t,f] += dot(resid[t,:], Wenc[f,:]) + t_bias[f]
// 128x128 tile, 256 threads, 8x8 per thread, K-chunk 16
#define BM 128
#define BN 128
#define BK 16
__global__ __launch_bounds__(256) void k_encoder(
        const float* __restrict__ resid, const float* __restrict__ Wenc,
        const float* __restrict__ t_bias, float* __restrict__ C) {
    __shared__ float As[BK][BM + 4];
    __shared__ float Bs[BK][BN + 4];
    int tid = threadIdx.x;
    int m0 = blockIdx.y * BM, n0 = blockIdx.x * BN;
    int mt = tid & 15, nt = tid >> 4;
    float acc[8][8] = {};
    for (int k0 = 0; k0 < D_DIM; k0 += BK) {
        if (tid < 128) {
            const float* ar = resid + (size_t)(m0 + tid) * D_DIM + k0;
            #pragma unroll
            for (int j = 0; j < BK; j += 4) {
                float4 t4 = *(const float4*)(ar + j);
                As[j][tid] = t4.x; As[j + 1][tid] = t4.y;
                As[j + 2][tid] = t4.z; As[j + 3][tid] = t4.w;
            }
        } else {
            int r = tid - 128;
            const float* br = Wenc + (size_t)(n0 + r) * D_DIM + k0;
            #pragma unroll
            for (int j = 0; j < BK; j += 4) {
                float4 t4 = *(const float4*)(br + j);
                Bs[j][r] = t4.x; Bs[j + 1][r] = t4.y;
                Bs[j + 2][r] = t4.z; Bs[j + 3][r] = t4.w;
            }
        }
        __syncthreads();
        #pragma unroll
        for (int k = 0; k < BK; ++k) {
            float a[8], bb[8];
            *(float4*)&a[0]  = *(const float4*)&As[k][mt * 8];
            *(float4*)&a[4]  = *(const float4*)&As[k][mt * 8 + 4];
            *(float4*)&bb[0] = *(const float4*)&Bs[k][nt * 8];
            *(float4*)&bb[4] = *(const float4*)&Bs[k][nt * 8 + 4];
            #pragma unroll
            for (int i = 0; i < 8; ++i)
                #pragma unroll
                for (int j = 0; j < 8; ++j) acc[i][j] += a[i] * bb[j];
        }
        __syncthreads();
    }
    float tb[8];
    #pragma unroll
    for (int j = 0; j < 8; ++j) tb[j] = t_bias[n0 + nt * 8 + j];
    #pragma unroll
    for (int i = 0; i < 8; ++i) {
        float* cr = C + (size_t)(m0 + mt * 8 + i) * F_DIM + n0 + nt * 8;
        #pragma unroll
        for (int j = 0; j < 8; ++j) cr[j] += acc[i][j] + tb[j];
    }
}

// ---------------------------------------------------------------------------
// K7: exact top-64 per token via histogram + exact boundary-bin selection;
// zeroes the row in-place and scatters relu'd top values; emits selection lists
__global__ __launch_bounds__(256) void k_select(
        float* __restrict__ C, int* __restrict__ sel_idx, float* __restrict__ sel_val) {
    __shared__ float row[F_DIM];      // 32KB
    __shared__ int hist[NBIN];        // 4KB
    __shared__ int bstar, nsure, ncand;
    __shared__ float sure_v[64];  __shared__ int sure_f[64];
    __shared__ float cand_v[256]; __shared__ int cand_f[256];
    __shared__ float out_v[KSEL]; __shared__ int out_f[KSEL];
    int t = blockIdx.x, tid = threadIdx.x;
    float* Crow = C + (size_t)t * F_DIM;
    for (int i = tid; i < F_DIM; i += 256) row[i] = Crow[i];
    for (int i = tid; i < NBIN; i += 256) hist[i] = 0;
    __syncthreads();
    for (int i = tid; i < F_DIM; i += 256) {
        int b = (int)floorf((row[i] + 16.0f) * 32.0f);
        b = b < 0 ? 0 : (b > NBIN - 1 ? NBIN - 1 : b);
        atomicAdd(&hist[b], 1);
    }
    __syncthreads();
    if (tid == 0) {
        int cum = 0, bs = 0;
        for (int b = NBIN - 1; b >= 0; --b) { cum += hist[b]; if (cum >= KSEL) { bs = b; break; } }
        bstar = bs; nsure = 0; ncand = 0;
    }
    __syncthreads();
    int bs = bstar;
    for (int i = tid; i < F_DIM; i += 256) {
        float v = row[i];
        int b = (int)floorf((v + 16.0f) * 32.0f);
        b = b < 0 ? 0 : (b > NBIN - 1 ? NBIN - 1 : b);
        if (b > bs) {
            int p = atomicAdd(&nsure, 1);
            if (p < 64) { sure_v[p] = v; sure_f[p] = i; }
        } else if (b == bs) {
            int p = atomicAdd(&ncand, 1);
            if (p < 256) { cand_v[p] = v; cand_f[p] = i; }
        }
    }
    __syncthreads();
    if (tid == 0) {
        int c1 = nsure; if (c1 > KSEL) c1 = KSEL;
        for (int i = 0; i < c1; ++i) { out_v[i] = sure_v[i]; out_f[i] = sure_f[i]; }
        int need = KSEL - c1;
        int nc = ncand; if (nc > 256) nc = 256;
        for (int s = 0; s < need; ++s) {       // exact selection, ties -> lower index
            float bv = -1e30f; int bf = 0x7fffffff, bi = -1;
            for (int i = 0; i < nc; ++i) {
                float v = cand_v[i];
                if (v > bv || (v == bv && cand_f[i] < bf)) { bv = v; bf = cand_f[i]; bi = i; }
            }
            if (bi < 0) { out_v[c1 + s] = 0.f; out_f[c1 + s] = 0; continue; }
            out_v[c1 + s] = cand_v[bi]; out_f[c1 + s] = cand_f[bi];
            cand_v[bi] = -1e30f;
        }
    }
    __syncthreads();
    for (int i = tid; i < F_DIM; i += 256) Crow[i] = 0.0f;
    __syncthreads();
    if (tid < KSEL) {
        float v = out_v[tid]; int f = out_f[tid];
        float rv = v > 0.f ? v : 0.f;
        Crow[f] = rv;
        sel_idx[t * KSEL + tid] = f;
        sel_val[t * KSEL + tid] = rv;
    }
}

// ---------------------------------------------------------------------------
// K8: sparse decode: recon[t,d] = sum_j sel_val[j]*Wdec[sel_idx[j],d] + bdec[d]
__global__ __launch_bounds__(256) void k_decode(
        const int* __restrict__ sel_idx, const float* __restrict__ sel_val,
        const float* __restrict__ Wdec, const float* __restrict__ bdec,
        float* __restrict__ recon) {
    __shared__ int sf[KSEL]; __shared__ float sv[KSEL];
    int t = blockIdx.x, tid = threadIdx.x;
    if (tid < KSEL) { sf[tid] = sel_idx[t * KSEL + tid]; sv[tid] = sel_val[t * KSEL + tid]; }
    __syncthreads();
    for (int d = tid; d < D_DIM; d += 256) {
        float s = bdec[d];
        #pragma unroll 8
        for (int j = 0; j < KSEL; ++j) s += sv[j] * Wdec[(size_t)sf[j] * D_DIM + d];
        recon[(size_t)t * D_DIM + d] = s;
    }
}

// ---------------------------------------------------------------------------
extern "C" void kernel_launch(void* const* d_in, const int* in_sizes, int n_in,
                              void* d_out, int out_size, void* d_ws, size_t ws_size,
                              hipStream_t stream) {
    (void)in_sizes; (void)n_in; (void)out_size; (void)ws_size;
    const float* resid   = (const float*)d_in[0];
    const float* pruned0 = (const float*)d_in[1];
    const float* pruned1 = (const float*)d_in[2];
    const float* Wenc    = (const float*)d_in[4];
    const float* benc    = (const float*)d_in[5];
    const float* Wdec    = (const float*)d_in[6];
    const float* bdec    = (const float*)d_in[7];
    const float* Wup0    = (const float*)d_in[8];
    const float* Wup1    = (const float*)d_in[9];
    const float* bup0    = (const float*)d_in[10];
    const float* bup1    = (const float*)d_in[11];
    const float* mask0   = (const float*)d_in[12];
    const float* mask1   = (const float*)d_in[13];

    char* ws = (char*)d_ws;
    size_t o = 0;
    auto alloc = [&](size_t bytes) -> char* {
        o = (o + 255) & ~(size_t)255;
        char* p = ws + o; o += bytes; return p;
    };
    float* t_bias   = (float*)alloc((size_t)F_DIM * 4);
    int*   cnt_tile = (int*)  alloc((size_t)2 * NFT * U_DIM * 4);
    int*   basep    = (int*)  alloc((size_t)2 * NFT * U_DIM * 4);
    int*   cnt_tot  = (int*)  alloc((size_t)2 * U_DIM * 4);
    u64*   bitmap   = (u64*)  alloc((size_t)2 * NFT * NUT * TILE * 4 * 8);
    u16*   csc_f    = (u16*)  alloc((size_t)2 * U_DIM * COLCAP * 2);
    float* csc_v    = (float*)alloc((size_t)2 * U_DIM * COLCAP * 4);
    int*   sel_idx  = (int*)  alloc((size_t)NTOK * KSEL * 4);
    float* sel_val  = (float*)alloc((size_t)NTOK * KSEL * 4);
    // total ws use ~74 MB

    float* out   = (float*)d_out;
    float* C     = out;                              // feat region doubles as approx scratch
    float* recon = out + (size_t)NTOK * F_DIM;

    hipLaunchKernelGGL(k_bias,       dim3(F_DIM / 4),        dim3(256), 0, stream,
                       Wenc, benc, bup0, bup1, t_bias);
    hipLaunchKernelGGL(k_mask_scan,  dim3(NUT, NFT, 2),      dim3(256), 0, stream,
                       mask0, mask1, cnt_tile, bitmap);
    hipLaunchKernelGGL(k_col_prefix, dim3(2 * U_DIM / 256),  dim3(256), 0, stream,
                       cnt_tile, basep, cnt_tot);
    hipLaunchKernelGGL(k_virt_build, dim3(NUT, NFT, 2),      dim3(256), 0, stream,
                       Wenc, Wup0, Wup1, bitmap, basep, csc_f, csc_v);
    hipLaunchKernelGGL(k_contrib,    dim3(NTOK),             dim3(512), 0, stream,
                       pruned0, pruned1, cnt_tot, csc_f, csc_v, C);
    hipLaunchKernelGGL(k_encoder,    dim3(F_DIM / BN, NTOK / BM), dim3(256), 0, stream,
                       resid, Wenc, t_bias, C);
    hipLaunchKernelGGL(k_select,     dim3(NTOK),             dim3(256), 0, stream,
                       C, sel_idx, sel_val);
    hipLaunchKernelGGL(k_decode,     dim3(NTOK),             dim3(256), 0, stream,
                       sel_idx, sel_val, Wdec, bdec, recon);
}